// Round 7
// baseline (180.718 us; speedup 1.0000x reference)
//
#include <hip/hip_runtime.h>
#include <cstdint>

// Problem constants
#define B_   64
#define CI_  384
#define CO_  384
#define HW_  784
#define E_   8

typedef unsigned short ushort_t;
typedef unsigned int   uint_t;

typedef __attribute__((ext_vector_type(8))) short bf16x8;   // 8 bf16 (4 VGPRs)
typedef __attribute__((ext_vector_type(4))) float f32x4;    // MFMA accumulator

__device__ __forceinline__ ushort_t f2bf_rne(float f) {
  uint_t u = __builtin_bit_cast(uint_t, f);
  u += 0x7fffu + ((u >> 16) & 1u);
  return (ushort_t)(u >> 16);
}

// Pack truncated-bf16 of (f0 -> low ushort, f1 -> high ushort) in one v_perm_b32.
__device__ __forceinline__ uint_t pack_bf16_trunc(float f0, float f1) {
  return __builtin_amdgcn_perm(__builtin_bit_cast(uint_t, f1),   // S0 -> bytes 4..7
                               __builtin_bit_cast(uint_t, f0),   // S1 -> bytes 0..3
                               0x07060302u);                     // {f1.b3,f1.b2,f0.b3,f0.b2}
}

// ---------------------------------------------------------------------------
// Kernel 1: agg[b,o,i] = sum_e r[b,e]*w[e,o,i] -> bf16. w read ONCE (38 MB
// total traffic, ~6 us). The xq workspace is GONE: its 77 MB of write+read
// round-trip moved into gemm as a direct f32 read of x (L2-hot per XCD).
// ---------------------------------------------------------------------------
#define AGG_BLOCKS 288               // CO_*CI_/512

__global__ __launch_bounds__(256) void prep_agg(const float* __restrict__ rw,
                                                const float* __restrict__ w,
                                                ushort_t* __restrict__ agg) {
  __shared__ float r[B_ * E_];
  const int tid = threadIdx.x;
  r[tid]       = rw[tid];
  r[tid + 256] = rw[tid + 256];
  const int base = blockIdx.x * 512 + tid * 2;  // flat (o,i) pair index
  float2 wv[E_];
#pragma unroll
  for (int e = 0; e < E_; ++e)
    wv[e] = *(const float2*)&w[e * (CO_ * CI_) + base];
  __syncthreads();
#pragma unroll 8
  for (int b = 0; b < B_; ++b) {
    float ax = 0.f, ay = 0.f;
#pragma unroll
    for (int e = 0; e < E_; ++e) {
      const float rv = r[b * E_ + e];
      ax += rv * wv[e].x;
      ay += rv * wv[e].y;
    }
    const uint_t v = (uint_t)f2bf_rne(ax) | ((uint_t)f2bf_rne(ay) << 16);
    *(uint_t*)&agg[(size_t)b * (CO_ * CI_) + base] = v;
  }
}

// ---------------------------------------------------------------------------
// Kernel 2: ring-3 counted-vmcnt GEMM; A DMA-staged, B reg-staged from f32 x.
//   out[b](384x784) = agg[b](384x384 bf16) @ x[b](384x784 f32 -> bf16 pack)
// 256 thr = 4 waves 2x2, BM=BN=128, BK=32, 12 K-steps.
// Per body(t):  s_waitcnt vmcnt(10)  [retires stage t: 2 A-gl_lds + 8 B-loads;
//               stage t+1 stays in flight]
//               PACKB(t): 8 v_perm + 2 ds_write_b128 into swizzled slots
//               lgkmcnt(0); raw s_barrier   [Bs/As of tile t visible to all]
//               issue stage t+2 (A DMA + B float2 loads -> freed reg set)
//               COMPUTE(t): ds_read frags + setprio'd 16-MFMA
// B slot map == A's: slot s holds (row=s>>2, q=(s&3)^((s>>3)&3)); writer uses
// s = col*4 + (waveq ^ ((col>>1)&3)); reader invariant content q == lq holds
// (16nf,64wn drop out of (col>>1)&3) -> COMPUTE unchanged from round 6.
// Ring-3 WAR safety: identical distance argument as round 6 (passed 2x).
// LDS 48 KB -> 3 blocks/CU; ~155 VGPR under launch_bounds(256,3).
// Grid (8, 168): x == XCD; y packs (bg, mt, nt) so one b's 21 tiles run
// consecutively per XCD (x[b] 1.2 MB + agg[b] 288 KB stay L2-hot).
// ---------------------------------------------------------------------------
#define BM 128
#define BN 128
#define BK 32
#define KIT (CI_ / BK)     // 12

__global__ __launch_bounds__(256, 3) void moe_gemm5(const float* __restrict__ X,
                                                    const ushort_t* __restrict__ Agg,
                                                    float* __restrict__ Out) {
  __shared__ __align__(16) ushort_t As[3][BM * BK];  // 3 x 8 KB
  __shared__ __align__(16) ushort_t Bs[3][BN * BK];  // 3 x 8 KB

  const int tid  = threadIdx.x;
  const int lane = tid & 63;
  const int wave = tid >> 6;
  const int wm = wave & 1, wn = wave >> 1;

  const int bx = blockIdx.x;           // 0..7  == XCD id (linear%8 round-robin)
  const int by = blockIdx.y;           // 0..167
  const int bg  = by / 21;
  const int rem = by - bg * 21;
  const int mt  = rem / 7;             // 0..2
  const int nt  = rem - mt * 7;        // 0..6
  const int b   = bg * 8 + bx;

  // ---- A staging (DMA): slot s = (row=s>>2, q=(s&3)^((s>>3)&3)) ----
  const int sr0 = tid >> 2,          sq0 = (tid & 3) ^ ((tid >> 3) & 3);
  const int sr1 = (tid + 256) >> 2,  sq1 = (tid & 3) ^ (((tid + 256) >> 3) & 3);
  const ushort_t* Ab = Agg + (size_t)b * CO_ * CI_ + (size_t)(mt * BM) * CI_;
  const ushort_t* Asrc0 = Ab + sr0 * CI_ + sq0 * 8;
  const ushort_t* Asrc1 = Ab + sr1 * CI_ + sq1 * 8;

  // ---- B staging (reg): thread owns cols (n0, n0+1), k-octet = wave ----
  const int n0  = (tid & 63) * 2;
  const int khq = wave;                              // k-octet index 0..3
  const int s0  = n0 * 4 + (khq ^ ((n0 >> 1) & 3));  // swizzled slot for col n0
  const int bws0 = s0 * 8;                           // ushort index (16B slot)
  const int bws1 = bws0 + 32;                        // col n0+1 -> slot s0+4
  int gn0 = nt * BN + n0;
  gn0 = gn0 > (HW_ - 2) ? (HW_ - 2) : gn0;           // clamp, pair in-bounds
  const float* XbCol = X + (size_t)b * CI_ * HW_ + (size_t)khq * 8 * HW_ + gn0;

  // ---- fragment read coords ----
  const int l15 = lane & 15;
  const int lq  = lane >> 4;
  const int xqA = lq ^ ((l15 >> 1) & 3);   // swizzled q (content q == lq)

  f32x4 acc[4][4];
#pragma unroll
  for (int i = 0; i < 4; ++i)
#pragma unroll
    for (int j = 0; j < 4; ++j)
      acc[i][j] = (f32x4)0.f;

  float2 vA[8], vB[8];   // two in-flight B stages (named sets, static index)

#define STAGE_A(PB, KK)                                                        \
  {                                                                            \
    __builtin_amdgcn_global_load_lds(                                          \
        (const __attribute__((address_space(1))) uint_t*)(Asrc0 + (KK) * BK),  \
        (__attribute__((address_space(3))) uint_t*)&As[PB][tid * 8], 16, 0, 0);\
    __builtin_amdgcn_global_load_lds(                                          \
        (const __attribute__((address_space(1))) uint_t*)(Asrc1 + (KK) * BK),  \
        (__attribute__((address_space(3))) uint_t*)&As[PB][(tid + 256) * 8],   \
        16, 0, 0);                                                             \
  }

#define LOADB(SET, KK)                                                         \
  {                                                                            \
    const float* p_ = XbCol + (size_t)((KK) * BK) * HW_;                       \
    _Pragma("unroll") for (int j_ = 0; j_ < 8; ++j_)                           \
        SET[j_] = *(const float2*)(p_ + (size_t)j_ * HW_);                     \
  }

#define PACKB(SET, PB)                                                         \
  {                                                                            \
    uint4 u0_, u1_;                                                            \
    u0_.x = pack_bf16_trunc(SET[0].x, SET[1].x);                               \
    u0_.y = pack_bf16_trunc(SET[2].x, SET[3].x);                               \
    u0_.z = pack_bf16_trunc(SET[4].x, SET[5].x);                               \
    u0_.w = pack_bf16_trunc(SET[6].x, SET[7].x);                               \
    u1_.x = pack_bf16_trunc(SET[0].y, SET[1].y);                               \
    u1_.y = pack_bf16_trunc(SET[2].y, SET[3].y);                               \
    u1_.z = pack_bf16_trunc(SET[4].y, SET[5].y);                               \
    u1_.w = pack_bf16_trunc(SET[6].y, SET[7].y);                               \
    *(uint4*)&Bs[PB][bws0] = u0_;                                              \
    *(uint4*)&Bs[PB][bws1] = u1_;                                              \
  }

#define COMPUTE(CB)                                                            \
  {                                                                            \
    bf16x8 a[4], bb[4];                                                        \
    _Pragma("unroll") for (int mf = 0; mf < 4; ++mf) {                         \
      const int row = wm * 64 + mf * 16 + l15;                                 \
      a[mf] = *(const bf16x8*)&As[CB][(row * 4 + xqA) * 8];                    \
    }                                                                          \
    _Pragma("unroll") for (int nf = 0; nf < 4; ++nf) {                         \
      const int col = wn * 64 + nf * 16 + l15;                                 \
      bb[nf] = *(const bf16x8*)&Bs[CB][(col * 4 + xqA) * 8];                   \
    }                                                                          \
    __builtin_amdgcn_s_setprio(1);                                             \
    _Pragma("unroll") for (int mf = 0; mf < 4; ++mf)                           \
      _Pragma("unroll") for (int nf = 0; nf < 4; ++nf)                         \
        acc[mf][nf] = __builtin_amdgcn_mfma_f32_16x16x32_bf16(a[mf], bb[nf],   \
                                                              acc[mf][nf],     \
                                                              0, 0, 0);        \
    __builtin_amdgcn_s_setprio(0);                                             \
  }

// One K-step. VMSTR: "10" steady (retire stage T, keep T+1 flying), "0" last.
#define BODY(T, SET, VMSTR, STG_EN)                                            \
  {                                                                            \
    asm volatile("s_waitcnt vmcnt(" VMSTR ")" ::: "memory");                   \
    __builtin_amdgcn_sched_barrier(0);                                         \
    PACKB(SET, (T) % 3);                                                       \
    asm volatile("s_waitcnt lgkmcnt(0)" ::: "memory");                         \
    __builtin_amdgcn_s_barrier();                                              \
    __builtin_amdgcn_sched_barrier(0);                                         \
    if (STG_EN) {                                                              \
      STAGE_A(((T) + 2) % 3, (T) + 2);                                         \
      LOADB(SET, (T) + 2);                                                     \
    }                                                                          \
    COMPUTE((T) % 3);                                                          \
    __builtin_amdgcn_sched_barrier(0);                                         \
  }

  // ---- Prologue: stages 0,1 in flight (20 vmcnt events outstanding) ----
  STAGE_A(0, 0); LOADB(vA, 0);
  STAGE_A(1, 1); LOADB(vB, 1);

  BODY(0, vA, "10", 1)
  BODY(1, vB, "10", 1)
  BODY(2, vA, "10", 1)
  BODY(3, vB, "10", 1)
  BODY(4, vA, "10", 1)
  BODY(5, vB, "10", 1)
  BODY(6, vA, "10", 1)
  BODY(7, vB, "10", 1)
  BODY(8, vA, "10", 1)
  BODY(9, vB, "10", 1)
  BODY(10, vA, "10", 0)
  BODY(11, vB, "0", 0)

  // ---- Epilogue: C/D layout col=lane&15 (n), row=(lane>>4)*4+reg (m) ----
  float* Ob = Out + (size_t)b * CO_ * HW_;
#pragma unroll
  for (int mf = 0; mf < 4; ++mf) {
#pragma unroll
    for (int nf = 0; nf < 4; ++nf) {
      const int n = nt * BN + wn * 64 + nf * 16 + l15;
      if (n < HW_) {
        const int mbase = mt * BM + wm * 64 + mf * 16 + lq * 4;
#pragma unroll
        for (int r = 0; r < 4; ++r)
          Ob[(size_t)(mbase + r) * HW_ + n] = acc[mf][nf][r];
      }
    }
  }
}

// ---------------------------------------------------------------------------
// Workspace: agg bf16 [64][384][384] = 18.9 MB only (xq eliminated).
// ---------------------------------------------------------------------------
extern "C" void kernel_launch(void* const* d_in, const int* in_sizes, int n_in,
                              void* d_out, int out_size, void* d_ws, size_t ws_size,
                              hipStream_t stream) {
  const float* x  = (const float*)d_in[0];  // [64,384,28,28] f32
  const float* rw = (const float*)d_in[1];  // [64,8] f32
  const float* w  = (const float*)d_in[2];  // [8,384,384] f32
  float* out = (float*)d_out;               // [64,384,28,28] f32

  ushort_t* agg = (ushort_t*)d_ws;

  prep_agg<<<AGG_BLOCKS, 256, 0, stream>>>(rw, w, agg);
  moe_gemm5<<<dim3(8, 21 * (B_ / 8)), 256, 0, stream>>>(x, agg, out);
}

// Round 8
// 174.159 us; speedup vs baseline: 1.0377x; 1.0377x over previous
//
#include <hip/hip_runtime.h>
#include <cstdint>

// Problem constants
#define B_   64
#define CI_  384
#define CO_  384
#define HW_  784
#define E_   8
#define G_   (CI_ / 8)   // 48 ci-octets

typedef unsigned short ushort_t;
typedef unsigned int   uint_t;

typedef __attribute__((ext_vector_type(8))) short bf16x8;   // 8 bf16 (4 VGPRs)
typedef __attribute__((ext_vector_type(4))) float f32x4;    // MFMA accumulator

#define AS1 __attribute__((address_space(1)))
#define AS3 __attribute__((address_space(3)))

__device__ __forceinline__ ushort_t f2bf_rne(float f) {
  uint_t u = __builtin_bit_cast(uint_t, f);
  u += 0x7fffu + ((u >> 16) & 1u);
  return (ushort_t)(u >> 16);
}

__device__ __forceinline__ uint_t pack_bf16_trunc(float f0, float f1) {
  return __builtin_amdgcn_perm(__builtin_bit_cast(uint_t, f1),
                               __builtin_bit_cast(uint_t, f0),
                               0x07060302u);
}

// ---------------------------------------------------------------------------
// Kernel 1 (fused prep, back from R6 -- the xq+bf16-DMA pipeline is the
// proven-fast combination; R7 showed f32-B-in-gemm costs more than xq saves):
//  blocks [0, 288):    agg[b,o,i] = sum_e r[b,e]*w[e,o,i] -> bf16 (w read once)
//  blocks [288, 3360): xq[b][g][hw][j] = bf16(x[b][g*8+j][hw])
// ---------------------------------------------------------------------------
#define AGG_BLOCKS 288
#define XQ_BLOCKS  (G_ * B_)         // 3072

__global__ __launch_bounds__(256) void prep(const float* __restrict__ rw,
                                            const float* __restrict__ w,
                                            const float* __restrict__ x,
                                            ushort_t* __restrict__ agg,
                                            ushort_t* __restrict__ xq) {
  __shared__ float r[B_ * E_];
  const int blk = blockIdx.x;
  const int tid = threadIdx.x;

  if (blk < AGG_BLOCKS) {
    r[tid]       = rw[tid];
    r[tid + 256] = rw[tid + 256];
    const int base = blk * 512 + tid * 2;
    float2 wv[E_];
#pragma unroll
    for (int e = 0; e < E_; ++e)
      wv[e] = *(const float2*)&w[e * (CO_ * CI_) + base];
    __syncthreads();
#pragma unroll 8
    for (int b = 0; b < B_; ++b) {
      float ax = 0.f, ay = 0.f;
#pragma unroll
      for (int e = 0; e < E_; ++e) {
        const float rv = r[b * E_ + e];
        ax += rv * wv[e].x;
        ay += rv * wv[e].y;
      }
      const uint_t v = (uint_t)f2bf_rne(ax) | ((uint_t)f2bf_rne(ay) << 16);
      *(uint_t*)&agg[(size_t)b * (CO_ * CI_) + base] = v;
    }
  } else {
    const int idx = blk - AGG_BLOCKS;
    const int g = idx % G_;
    const int b = idx / G_;
    const float* xp = x + ((size_t)b * CI_ + g * 8) * HW_;
    ushort_t* op = xq + (((size_t)b * G_ + g) * HW_) * 8;
#pragma unroll
    for (int c = 0; c < 4; ++c) {
      const int hw = c * 256 + tid;
      if (hw < HW_) {
        float v[8];
#pragma unroll
        for (int j = 0; j < 8; ++j) v[j] = xp[(size_t)j * HW_ + hw];
        uint4 u;
        u.x = pack_bf16_trunc(v[0], v[1]);
        u.y = pack_bf16_trunc(v[2], v[3]);
        u.z = pack_bf16_trunc(v[4], v[5]);
        u.w = pack_bf16_trunc(v[6], v[7]);
        *(uint4*)&op[hw * 8] = u;
      }
    }
  }
}

// ---------------------------------------------------------------------------
// Kernel 2: full-M tile GEMM -- minimize STAGED BYTES (the measured ~10-12
// B/cyc/CU per-CU load-service wall that explains all 7 prior variants).
//   Tile (b, nt): 384 rows x 112 cols (zero tails). Staged bytes total =
//   7 x agg + 1 x xq = 171 MB vs R6's 258 MB (-34%).
// 768 thr = 12 waves, wave-tile 32x112 (acc[2][7], 14 MFMA/body/wave).
// LDS: A ring-2 (2x24KB) + B ring-3 (3x7KB) = 69 KB; 12 waves/CU (1 block).
// Counted vmcnt: body t waits OWN stage-t ops -> barrier -> issue A(t+1)
// (ring-2 WAR-safe: all reads of that buf finished before barrier) and
// B(t+2) -> compute tile t. Waves 0-6 stage B (448 slots), waves 7-11 are
// A-only -> wave-uniform vmcnt literals (1 vs 0); B visibility via barrier.
// Grid (8, 56): x == XCD; all 7 nt of one b on one XCD (agg[b] L2-hot x7).
// ---------------------------------------------------------------------------
#define TN 112
#define BK 32
#define KIT (CI_ / BK)     // 12

__global__ __launch_bounds__(768, 4) void moe_gemm6(const ushort_t* __restrict__ Xq,
                                                    const ushort_t* __restrict__ Agg,
                                                    float* __restrict__ Out) {
  __shared__ __align__(16) ushort_t As[2][CO_ * BK];   // 2 x 24 KB (384 rows)
  __shared__ __align__(16) ushort_t Bs[3][TN * BK];    // 3 x 7 KB

  const int tid  = threadIdx.x;
  const int lane = tid & 63;
  const int w    = tid >> 6;          // wave 0..11 -> rows w*32..w*32+31
  const int l15  = lane & 15;
  const int lq   = lane >> 4;
  const int xqA  = lq ^ ((l15 >> 1) & 3);   // swizzled q (content q == lq)

  const int bx = blockIdx.x;          // 0..7 == XCD id (linear%8 round-robin)
  const int by = blockIdx.y;          // 0..55
  const int bg = by / 7;
  const int nt = by - bg * 7;
  const int b  = bg * 8 + bx;

  // ---- A staging: slots tid, tid+768 (rows 0..191, 192..383) ----
  // slot s: row = s>>2, q = (s&3)^((s>>3)&3); +768 leaves q unchanged.
  const int sq0 = (tid & 3) ^ ((tid >> 3) & 3);
  const int sr0 = tid >> 2;
  const ushort_t* Ab = Agg + (size_t)b * CO_ * CI_;
  const ushort_t* Asrc0 = Ab + sr0 * CI_ + sq0 * 8;
  const ushort_t* Asrc1 = Ab + (sr0 + 192) * CI_ + sq0 * 8;

  // ---- B staging: threads 0..447 own one slot; waves 7-11 A-only ----
  const int bcol = tid >> 2;                       // 0..111 (valid tid<448)
  const int bq   = (tid & 3) ^ ((tid >> 3) & 3);
  const ushort_t* Xb = Xq + (size_t)b * G_ * HW_ * 8;
  const ushort_t* Bsrc = Xb + ((size_t)bq * HW_ + nt * TN + bcol) * 8;

  f32x4 acc[2][7];
#pragma unroll
  for (int i = 0; i < 2; ++i)
#pragma unroll
    for (int j = 0; j < 7; ++j)
      acc[i][j] = (f32x4)0.f;

#define STAGE_A(PB, KK)                                                        \
  {                                                                            \
    __builtin_amdgcn_global_load_lds(                                          \
        (const AS1 uint_t*)(Asrc0 + (KK) * BK),                                \
        (AS3 uint_t*)&As[PB][tid * 8], 16, 0, 0);                              \
    __builtin_amdgcn_global_load_lds(                                          \
        (const AS1 uint_t*)(Asrc1 + (KK) * BK),                                \
        (AS3 uint_t*)&As[PB][(tid + 768) * 8], 16, 0, 0);                      \
  }

#define STAGE_B(PB, KK)                                                        \
  {                                                                            \
    if (tid < 448)                                                             \
      __builtin_amdgcn_global_load_lds(                                        \
          (const AS1 uint_t*)(Bsrc + (size_t)(KK) * (4 * HW_ * 8)),            \
          (AS3 uint_t*)&Bs[PB][tid * 8], 16, 0, 0);                            \
  }

#define COMPUTE(AB, BB)                                                        \
  {                                                                            \
    bf16x8 a[2], bb[7];                                                        \
    _Pragma("unroll") for (int mf = 0; mf < 2; ++mf) {                         \
      const int row = w * 32 + mf * 16 + l15;                                  \
      a[mf] = *(const bf16x8*)&As[AB][(row * 4 + xqA) * 8];                    \
    }                                                                          \
    _Pragma("unroll") for (int nf = 0; nf < 7; ++nf) {                         \
      const int col = nf * 16 + l15;                                           \
      bb[nf] = *(const bf16x8*)&Bs[BB][(col * 4 + xqA) * 8];                   \
    }                                                                          \
    __builtin_amdgcn_s_setprio(1);                                             \
    _Pragma("unroll") for (int mf = 0; mf < 2; ++mf)                           \
      _Pragma("unroll") for (int nf = 0; nf < 7; ++nf)                         \
        acc[mf][nf] = __builtin_amdgcn_mfma_f32_16x16x32_bf16(a[mf], bb[nf],   \
                                                              acc[mf][nf],     \
                                                              0, 0, 0);        \
    __builtin_amdgcn_s_setprio(0);                                             \
  }

// Wave-uniform counted wait: B-staging waves keep B(t+1) in flight (vmcnt 1);
// A-only waves have nothing younger than stage t (vmcnt 0).
#define WAITV(N7)                                                              \
  {                                                                            \
    if (w < 7) { asm volatile("s_waitcnt vmcnt(" N7 ")" ::: "memory"); }       \
    else       { asm volatile("s_waitcnt vmcnt(0)" ::: "memory"); }            \
  }

// Body t: wait own stage-t -> barrier (stage t visible to all; frees A ring-2
// buf and B ring-3 buf for rewrite) -> issue A(t+1), B(t+2) -> compute t.
#define BODY(T, N7)                                                            \
  {                                                                            \
    WAITV(N7);                                                                 \
    __builtin_amdgcn_s_barrier();                                              \
    __builtin_amdgcn_sched_barrier(0);                                         \
    if ((T) + 1 < KIT) STAGE_A(((T) + 1) & 1, (T) + 1);                        \
    if ((T) + 2 < KIT) STAGE_B(((T) + 2) % 3, (T) + 2);                        \
    COMPUTE((T) & 1, (T) % 3);                                                 \
    __builtin_amdgcn_sched_barrier(0);                                         \
  }

  // ---- Prologue (issue order matters for vmcnt bookkeeping):
  //      B(0), A(0)x2, B(1)  -> body 0's vmcnt(1) retires B0,A0; keeps B1.
  STAGE_B(0, 0);
  STAGE_A(0, 0);
  STAGE_B(1, 1);

  BODY(0,  "1") BODY(1,  "1") BODY(2,  "1") BODY(3,  "1")
  BODY(4,  "1") BODY(5,  "1") BODY(6,  "1") BODY(7,  "1")
  BODY(8,  "1") BODY(9,  "1") BODY(10, "1") BODY(11, "0")

  // ---- Epilogue: C/D col=lane&15 (n), row=(lane>>4)*4+reg (m); zero tails ----
  float* Ob = Out + (size_t)b * CO_ * HW_ + nt * TN;
#pragma unroll
  for (int mf = 0; mf < 2; ++mf) {
#pragma unroll
    for (int nf = 0; nf < 7; ++nf) {
      const int n  = nf * 16 + l15;
      const int mb = w * 32 + mf * 16 + lq * 4;
#pragma unroll
      for (int r = 0; r < 4; ++r)
        Ob[(size_t)(mb + r) * HW_ + n] = acc[mf][nf][r];
    }
  }
}

// ---------------------------------------------------------------------------
// Workspace: agg bf16 [64][384][384] = 18.9 MB, xq bf16 [64][48][784][8] =
// 38.5 MB after it (57.4 MB total).
// ---------------------------------------------------------------------------
extern "C" void kernel_launch(void* const* d_in, const int* in_sizes, int n_in,
                              void* d_out, int out_size, void* d_ws, size_t ws_size,
                              hipStream_t stream) {
  const float* x  = (const float*)d_in[0];  // [64,384,28,28] f32
  const float* rw = (const float*)d_in[1];  // [64,8] f32
  const float* w  = (const float*)d_in[2];  // [8,384,384] f32
  float* out = (float*)d_out;               // [64,384,28,28] f32

  ushort_t* agg = (ushort_t*)d_ws;
  ushort_t* xq  = agg + (size_t)B_ * CO_ * CI_;   // + 18.9 MB

  prep<<<AGG_BLOCKS + XQ_BLOCKS, 256, 0, stream>>>(rw, w, x, agg, xq);
  moe_gemm6<<<dim3(8, 7 * (B_ / 8)), 768, 0, stream>>>(xq, agg, out);
}